// Round 14
// baseline (215.604 us; speedup 1.0000x reference)
//
#include <hip/hip_runtime.h>
#include <hip/hip_fp16.h>

// ---------------------------------------------------------------------------
// GCN pipeline. Round 27:
//  - GEMM-1 gets the r26 occupancy treatment: 32-row tile, 512t, 17.4KB LDS
//    -> 32 waves/CU (was 12). Same per-tile MFMA order -> bit-identical.
//    fused_hg now 512t; hist leg 512 edges/block.
//  - scatter_norm: 2 edges/thread (4 random count loads in flight).
//  - Everything else = r26 (best, 211us). 6 dispatches.
// ---------------------------------------------------------------------------

#define ELLK 48   // mult of 16
#define PB   32   // nodes per gather_pool block
#define GG   32   // nodes per gather_gemm block

typedef short bf16x8 __attribute__((ext_vector_type(8)));
typedef float f32x4  __attribute__((ext_vector_type(4)));

__device__ inline unsigned short f2bf_rne(float f) {
    unsigned u = __float_as_uint(f);
    unsigned r = (u + 0x7fffu + ((u >> 16) & 1u)) >> 16;
    return (unsigned short)r;
}
__device__ inline float bf2f(unsigned short h) {
    return __uint_as_float(((unsigned)h) << 16);
}

// ---- dispatch #1: weight split/transpose + zero(count, pooled, cnt) -----
__global__ __launch_bounds__(256) void wconv_zero(const float* __restrict__ W1,
                                                  const float* __restrict__ W2,
                                                  unsigned short* __restrict__ W1h,
                                                  unsigned short* __restrict__ W1l,
                                                  unsigned short* __restrict__ W2h,
                                                  unsigned short* __restrict__ W2l,
                                                  int* __restrict__ count,
                                                  float* __restrict__ pooled,
                                                  float* __restrict__ cnt, int N) {
    int tid = threadIdx.x;
    int b = blockIdx.x;
    if (b < 128) {
        int i = b * 256 + tid;               // 0..32767
        const float* W = (i < 16384) ? W1 : W2;
        unsigned short* Wh = (i < 16384) ? W1h : W2h;
        unsigned short* Wl = (i < 16384) ? W1l : W2l;
        int ii = i & 16383;
        int k = ii >> 7, n = ii & 127;
        float v = W[ii];
        unsigned short h = f2bf_rne(v);
        float lo = v - bf2f(h);
        int ct = n >> 4, nn = n & 15, ks = k >> 5, q = (k >> 3) & 3, j = k & 7;
        int oidx = (((ct * 4 + ks) * 64) + (q * 16 + nn)) * 8 + j;
        Wh[oidx] = h;
        Wl[oidx] = f2bf_rne(lo);
    } else {
        int idx = (b - 128) * 256 + tid;
        if (idx < N) count[idx] = 0;
        else if (idx < N + 8192) pooled[idx - N] = 0.f;
        else if (idx < N + 8256) cnt[idx - N - 8192] = 0.f;
    }
}

// ---- GEMM-1 body (512t, 8 waves, 32-row tile): OUT_fp16 = X_f32 @ W -----
// wave w: row-half w&1, col-pair (w>>1)*2. Per-tile MFMA order identical to
// the old 64-row body -> bit-identical results.
__device__ __forceinline__ void gemm_body32(const float* __restrict__ X,
                                            const unsigned short* __restrict__ Wfh,
                                            const unsigned short* __restrict__ Wfl,
                                            __half* __restrict__ OUT, int M, int blk) {
    __shared__ unsigned short Xh[32][136];
    __shared__ unsigned short Xl[32][136];
    int tid = threadIdx.x;
    int w = tid >> 6, l = tid & 63;
    int m0 = blk * 32;

#pragma unroll
    for (int it = 0; it < 2; it++) {
        int i = tid + it * 512;
        int row = i >> 5, c4 = i & 31;
        int grow = m0 + row;
        float4 v = make_float4(0.f, 0.f, 0.f, 0.f);
        if (grow < M) v = *(const float4*)(X + (size_t)grow * 128 + c4 * 4);
        float a[4] = {v.x, v.y, v.z, v.w};
        ushort4 hi, lo;
        unsigned short* hp = (unsigned short*)&hi;
        unsigned short* lp = (unsigned short*)&lo;
#pragma unroll
        for (int e = 0; e < 4; e++) {
            unsigned short h = f2bf_rne(a[e]);
            hp[e] = h;
            lp[e] = f2bf_rne(a[e] - bf2f(h));
        }
        *(ushort4*)&Xh[row][c4 * 4] = hi;
        *(ushort4*)&Xl[row][c4 * 4] = lo;
    }
    __syncthreads();

    int q = l >> 4, nn = l & 15;
    int w2 = w & 1;
    int ch = (w >> 1) * 2;
    f32x4 acc[2];
#pragma unroll
    for (int ct2 = 0; ct2 < 2; ct2++) acc[ct2] = (f32x4){0.f, 0.f, 0.f, 0.f};
#pragma unroll
    for (int ks = 0; ks < 4; ks++) {
        bf16x8 ahi = *(const bf16x8*)&Xh[w2 * 16 + nn][ks * 32 + q * 8];
        bf16x8 alo = *(const bf16x8*)&Xl[w2 * 16 + nn][ks * 32 + q * 8];
#pragma unroll
        for (int ct2 = 0; ct2 < 2; ct2++) {
            int ct = ch + ct2;
            size_t fo = ((size_t)(ct * 4 + ks) * 64 + l) * 8;
            bf16x8 bhi = *(const bf16x8*)(Wfh + fo);
            bf16x8 blo = *(const bf16x8*)(Wfl + fo);
            acc[ct2] = __builtin_amdgcn_mfma_f32_16x16x32_bf16(ahi, bhi, acc[ct2], 0, 0, 0);
            acc[ct2] = __builtin_amdgcn_mfma_f32_16x16x32_bf16(alo, bhi, acc[ct2], 0, 0, 0);
            acc[ct2] = __builtin_amdgcn_mfma_f32_16x16x32_bf16(ahi, blo, acc[ct2], 0, 0, 0);
        }
    }
    __syncthreads();   // reuse Xh as fp16 epilogue buffer
#pragma unroll
    for (int r = 0; r < 4; r++) {
        int lrow = w2 * 16 + q * 4 + r;
#pragma unroll
        for (int ct2 = 0; ct2 < 2; ct2++) {
            __half hv = __float2half(acc[ct2][r]);
            Xh[lrow][(ch + ct2) * 16 + nn] = __half_as_ushort(hv);
        }
    }
    __syncthreads();
    {
        int c = tid;                            // 512 = 32 rows x 16 segs
        int row = c >> 4, seg = c & 15;
        int grow = m0 + row;
        if (grow < M) {
            uint4 v = *(uint4*)&Xh[row][seg * 8];
            *(uint4*)((unsigned short*)OUT + (size_t)grow * 128 + seg * 8) = v;
        }
    }
}

// fat kernel (512t): blocks [0,g2blocks) = GEMM-1; rest = hist+rank.
__global__ __launch_bounds__(512) void fused_hg(const float* __restrict__ X,
                                                const unsigned short* __restrict__ Wfh,
                                                const unsigned short* __restrict__ Wfl,
                                                __half* __restrict__ OUT, int M, int g2blocks,
                                                const int* __restrict__ dst,
                                                int* __restrict__ count,
                                                unsigned short* __restrict__ rank, int E) {
    if ((int)blockIdx.x < g2blocks) {
        gemm_body32(X, Wfh, Wfl, OUT, M, blockIdx.x);
    } else {
        int e = ((int)blockIdx.x - g2blocks) * 512 + (int)threadIdx.x;
        if (e < E) {
            int d = dst[e];
            rank[e] = (unsigned short)atomicAdd(&count[d], 1);
        }
    }
}

// scatter leg (blocks < hb2): atomic-free packed ELL fill, 2 edges/thread.
// pad leg: zero (src=0,norm=0) slots [count, ceil16] (min 16) per node.
__global__ __launch_bounds__(256) void scatter_norm(const int* __restrict__ src,
                                                    const int* __restrict__ dst,
                                                    const unsigned short* __restrict__ rank,
                                                    const int* __restrict__ count,
                                                    int2* __restrict__ ell,
                                                    int E, int N, int hb2) {
    int b = blockIdx.x;
    int tid = threadIdx.x;
    if (b < hb2) {
        int base = b * 512;
        int e0 = base + tid, e1 = base + tid + 256;
        int s0 = 0, d0 = 0, r0 = 0, s1 = 0, d1 = 0, r1 = 0;
        if (e0 < E) { s0 = src[e0]; d0 = dst[e0]; r0 = rank[e0]; }
        if (e1 < E) { s1 = src[e1]; d1 = dst[e1]; r1 = rank[e1]; }
        int cs0 = 0, cd0 = 0, cs1 = 0, cd1 = 0;
        if (e0 < E) { cs0 = count[s0]; cd0 = count[d0]; }
        if (e1 < E) { cs1 = count[s1]; cd1 = count[d1]; }
        if (e0 < E && r0 < ELLK) {
            float ds = 1.0f / sqrtf((float)cs0 + 1.0f);
            float dd = 1.0f / sqrtf((float)cd0 + 1.0f);
            ell[(size_t)d0 * ELLK + r0] = make_int2(s0, __float_as_int(ds * dd));
        }
        if (e1 < E && r1 < ELLK) {
            float ds = 1.0f / sqrtf((float)cs1 + 1.0f);
            float dd = 1.0f / sqrtf((float)cd1 + 1.0f);
            ell[(size_t)d1 * ELLK + r1] = make_int2(s1, __float_as_int(ds * dd));
        }
    } else {
        int n = (b - hb2) * 256 + tid;
        if (n < N) {
            int r = min(count[n], ELLK);
            int rend = min(ELLK, max(16, (r + 15) & ~15));
            int2 z = make_int2(0, 0);
            for (int j = r; j < rend; j++) ell[(size_t)n * ELLK + j] = z;
        }
    }
}

// ---- 8B-row fma: 4 halves * weight into a[4] ----------------------------
__device__ __forceinline__ void fma4(uint2 raw, float nr, float a[4]) {
    __half2 h0 = *(__half2*)&raw.x, h1 = *(__half2*)&raw.y;
    float2 f0 = __half22float2(h0), f1 = __half22float2(h1);
    a[0] = fmaf(f0.x, nr, a[0]); a[1] = fmaf(f0.y, nr, a[1]);
    a[2] = fmaf(f1.x, nr, a[2]); a[3] = fmaf(f1.y, nr, a[3]);
}

// ---- one node, em from LDS (32 slots staged), 8 loads in flight ---------
__device__ __forceinline__ void gather_node8(const unsigned short* __restrict__ hb,
                                             const long long* __restrict__ em_row,   // LDS
                                             const long long* __restrict__ ell_row,  // global (tail)
                                             int n, int cn, int sub2, int cl2,
                                             float a[4]) {
    int2 v[8];
#pragma unroll
    for (int k = 0; k < 8; k++) *(long long*)&v[k] = em_row[sub2 + k * 2];
    float din = 1.0f / sqrtf((float)cn + 1.0f);
    uint2 sr = *(const uint2*)(hb + (size_t)n * 128 + cl2 * 4);
    uint2 r[8];
#pragma unroll
    for (int k = 0; k < 8; k++) r[k] = *(const uint2*)(hb + (size_t)v[k].x * 128 + cl2 * 4);
    fma4(sr, sub2 == 0 ? din * din : 0.f, a);
#pragma unroll
    for (int k = 0; k < 8; k++) fma4(r[k], __int_as_float(v[k].y), a);
    if (cn > 16) {                       // wave-uniform branch (~10% of nodes)
        int2 u[8];
#pragma unroll
        for (int k = 0; k < 8; k++) *(long long*)&u[k] = em_row[16 + sub2 + k * 2];
        uint2 q[8];
#pragma unroll
        for (int k = 0; k < 8; k++) q[k] = *(const uint2*)(hb + (size_t)u[k].x * 128 + cl2 * 4);
#pragma unroll
        for (int k = 0; k < 8; k++) fma4(q[k], __int_as_float(u[k].y), a);
        if (cn > 32) {                   // ~never; global ELL slots 32..47
#pragma unroll
            for (int k = 0; k < 8; k++) {
                long long vv = ell_row[32 + sub2 + k * 2];
                uint2 qq = *(const uint2*)(hb + (size_t)(int)vv * 128 + cl2 * 4);
                fma4(qq, __int_as_float((int)(vv >> 32)), a);
            }
        }
    }
}

// ---- FUSED gather1 + gemm2 (512t, GG=32 nodes/block): Ah,ell -> Ah2 -----
__global__ __launch_bounds__(512) void gather_gemm(const __half* __restrict__ h,
                                                   const float* __restrict__ bias,
                                                   const int* __restrict__ count,
                                                   const long long* __restrict__ ell,
                                                   const unsigned short* __restrict__ Wfh,
                                                   const unsigned short* __restrict__ Wfl,
                                                   __half* __restrict__ OUT, int N) {
    __shared__ long long em_l[GG * 32];          // 8 KB
    __shared__ int cnt_l[GG];
    __shared__ unsigned short Xh[GG][136];       // 8.7 KB
    __shared__ unsigned short Xl[GG][136];
    int tid = threadIdx.x;
    int w = tid >> 6, l = tid & 63;
    int sub2 = l >> 5, cl2 = l & 31;
    int m0 = blockIdx.x * GG;
    const unsigned short* hb = (const unsigned short*)h;

    // stage em (32 slots/node) + counts, coalesced
    for (int i = tid; i < GG * 32; i += 512) {
        int node = i >> 5, slot = i & 31;
        int ne = min(m0 + node, N - 1);
        em_l[i] = ell[(size_t)ne * ELLK + slot];
    }
    if (tid < GG) cnt_l[tid] = count[min(m0 + tid, N - 1)];
    __syncthreads();

    float b4[4];
#pragma unroll
    for (int k = 0; k < 4; k++) b4[k] = bias[cl2 * 4 + k];

    // Phase A: 4 nodes per wave
    for (int rr = 0; rr < 4; rr++) {
        int lrow = w * 4 + rr;
        int n = m0 + lrow;
        int ne = min(n, N - 1);
        float a[4] = {0.f, 0.f, 0.f, 0.f};
        gather_node8(hb, em_l + lrow * 32, ell + (size_t)ne * ELLK,
                     ne, cnt_l[lrow], sub2, cl2, a);
#pragma unroll
        for (int k = 0; k < 4; k++) a[k] += __shfl_xor(a[k], 32, 64);
        if (sub2 == 0) {
            unsigned short hs[4], ls[4];
#pragma unroll
            for (int k = 0; k < 4; k++) {
                float vv = fmaxf(a[k] + b4[k], 0.f);
                unsigned short hh = f2bf_rne(vv);
                hs[k] = hh;
                ls[k] = f2bf_rne(vv - bf2f(hh));
            }
            *(ushort4*)&Xh[lrow][cl2 * 4] = *(ushort4*)hs;
            *(ushort4*)&Xl[lrow][cl2 * 4] = *(ushort4*)ls;
        }
    }
    __syncthreads();

    // Phase B: 8-wave MFMA over 32x128 tile
    int q = l >> 4, nn = l & 15;
    int w2 = w & 1;
    int ch = (w >> 1) * 2;
    f32x4 acc[2];
#pragma unroll
    for (int ct2 = 0; ct2 < 2; ct2++) acc[ct2] = (f32x4){0.f, 0.f, 0.f, 0.f};
#pragma unroll
    for (int ks = 0; ks < 4; ks++) {
        bf16x8 ahi = *(const bf16x8*)&Xh[w2 * 16 + nn][ks * 32 + q * 8];
        bf16x8 alo = *(const bf16x8*)&Xl[w2 * 16 + nn][ks * 32 + q * 8];
#pragma unroll
        for (int ct2 = 0; ct2 < 2; ct2++) {
            int ct = ch + ct2;
            size_t fo = ((size_t)(ct * 4 + ks) * 64 + l) * 8;
            bf16x8 bhi = *(const bf16x8*)(Wfh + fo);
            bf16x8 blo = *(const bf16x8*)(Wfl + fo);
            acc[ct2] = __builtin_amdgcn_mfma_f32_16x16x32_bf16(ahi, bhi, acc[ct2], 0, 0, 0);
            acc[ct2] = __builtin_amdgcn_mfma_f32_16x16x32_bf16(alo, bhi, acc[ct2], 0, 0, 0);
            acc[ct2] = __builtin_amdgcn_mfma_f32_16x16x32_bf16(ahi, blo, acc[ct2], 0, 0, 0);
        }
    }
    __syncthreads();   // reuse Xh as fp16 epilogue buffer
#pragma unroll
    for (int r = 0; r < 4; r++) {
        int lrow = w2 * 16 + q * 4 + r;
#pragma unroll
        for (int ct2 = 0; ct2 < 2; ct2++) {
            __half hv = __float2half(acc[ct2][r]);
            Xh[lrow][(ch + ct2) * 16 + nn] = __half_as_ushort(hv);
        }
    }
    __syncthreads();
    {
        int c = tid;                            // 512 = 32 rows x 16 segs
        int row = c >> 4, seg = c & 15;
        int grow = m0 + row;
        if (grow < N) {
            uint4 v = *(uint4*)&Xh[row][seg * 8];
            *(uint4*)((unsigned short*)OUT + (size_t)grow * 128 + seg * 8) = v;
        }
    }
}

// ---- FUSED gather2 + pool (512t, 32 nodes/block): -> pooled/cnt ---------
__global__ __launch_bounds__(512) void gather_pool(const __half* __restrict__ h,
                                                   const float* __restrict__ bias,
                                                   const int* __restrict__ count,
                                                   const long long* __restrict__ ell,
                                                   const int* __restrict__ batch,
                                                   float* __restrict__ pooled,
                                                   float* __restrict__ cnt, int N) {
    __shared__ long long em_l[PB * 32];          // 8 KB
    __shared__ int cnt_l[PB];
    __shared__ float P[PB][128];                 // 16 KB
    __shared__ int gb[PB];
    int tid = threadIdx.x;
    int w = tid >> 6, l = tid & 63;
    int sub2 = l >> 5, cl2 = l & 31;
    int m0 = blockIdx.x * PB;
    const unsigned short* hb = (const unsigned short*)h;

    for (int i = tid; i < PB * 32; i += 512) {
        int node = i >> 5, slot = i & 31;
        int ne = min(m0 + node, N - 1);
        em_l[i] = ell[(size_t)ne * ELLK + slot];
    }
    if (tid < PB) {
        cnt_l[tid] = count[min(m0 + tid, N - 1)];
        gb[tid] = (m0 + tid < N) ? batch[m0 + tid] : -1;
    }
    __syncthreads();

    float b4[4];
#pragma unroll
    for (int k = 0; k < 4; k++) b4[k] = bias[cl2 * 4 + k];

    // Phase A: 4 nodes per wave, results into P
    for (int rr = 0; rr < 4; rr++) {
        int lrow = w * 4 + rr;
        int n = m0 + lrow;
        int ne = min(n, N - 1);
        float a[4] = {0.f, 0.f, 0.f, 0.f};
        gather_node8(hb, em_l + lrow * 32, ell + (size_t)ne * ELLK,
                     ne, cnt_l[lrow], sub2, cl2, a);
#pragma unroll
        for (int k = 0; k < 4; k++) a[k] += __shfl_xor(a[k], 32, 64);
        if (sub2 == 0) {
            float4 o;
            o.x = fmaxf(a[0] + b4[0], 0.f);
            o.y = fmaxf(a[1] + b4[1], 0.f);
            o.z = fmaxf(a[2] + b4[2], 0.f);
            o.w = fmaxf(a[3] + b4[3], 0.f);
            *(float4*)&P[lrow][cl2 * 4] = o;
        }
    }
    __syncthreads();

    // Phase B: run-length pool, 2 half-groups x 16 rows (threads < 256)
    if (tid < 256) {
        int c = tid & 127, half = tid >> 7;
        float acc = 0.f, cacc = 0.f;
        int curg = -1;
        for (int i = half * 16; i < half * 16 + 16; i++) {
            int n = m0 + i;
            if (n >= N) break;
            int g = gb[i];
            float v = P[i][c];
            if (g != curg) {
                if (curg >= 0) {
                    atomicAdd(&pooled[curg * 128 + c], acc);
                    if (c == 0) atomicAdd(&cnt[curg], cacc);
                }
                curg = g; acc = 0.f; cacc = 0.f;
            }
            acc += v; cacc += 1.f;
        }
        if (curg >= 0) {
            atomicAdd(&pooled[curg * 128 + c], acc);
            if (c == 0) atomicAdd(&cnt[curg], cacc);
        }
    }
}

// ---- head: one wave per graph ------------------------------------------
__global__ __launch_bounds__(64) void head_kernel(const float* __restrict__ pooled,
                                                  const float* __restrict__ cnt,
                                                  const float* __restrict__ Wfc1,
                                                  const float* __restrict__ bfc1,
                                                  const float* __restrict__ Wfc2,
                                                  const float* __restrict__ bfc2,
                                                  float* __restrict__ out) {
    __shared__ float mean[128];
    int g = blockIdx.x;
    int t = threadIdx.x;
    float inv = 1.0f / fmaxf(cnt[g], 1.0f);
    mean[t] = pooled[g * 128 + t] * inv;
    mean[t + 64] = pooled[g * 128 + t + 64] * inv;
    __syncthreads();
    float s = bfc1[t];
#pragma unroll 4
    for (int k = 0; k < 128; k++) s = fmaf(mean[k], Wfc1[k * 64 + t], s);
    float p = fmaxf(s, 0.f) * Wfc2[t];
#pragma unroll
    for (int o = 32; o > 0; o >>= 1) p += __shfl_down(p, o, 64);
    if (t == 0) out[g] = p + bfc2[0];
}

extern "C" void kernel_launch(void* const* d_in, const int* in_sizes, int n_in,
                              void* d_out, int out_size, void* d_ws, size_t ws_size,
                              hipStream_t stream) {
    const float* x    = (const float*)d_in[0];
    const int*   edge = (const int*)d_in[1];
    const int*   batch= (const int*)d_in[2];
    const float* W1   = (const float*)d_in[3];
    const float* b1   = (const float*)d_in[4];
    const float* W2   = (const float*)d_in[5];
    const float* b2   = (const float*)d_in[6];
    const float* Wfc1 = (const float*)d_in[7];
    const float* bfc1 = (const float*)d_in[8];
    const float* Wfc2 = (const float*)d_in[9];
    const float* bfc2 = (const float*)d_in[10];
    float* out = (float*)d_out;

    int N = in_sizes[0] / 128;
    int E = in_sizes[1] / 2;
    const int* src = edge;
    const int* dst = edge + E;

    char* ws = (char*)d_ws;
    size_t off = 0;
    auto alloc = [&](size_t bytes) { void* p = ws + off; off += (bytes + 255) & ~(size_t)255; return p; };
    __half* Ah    = (__half*)alloc((size_t)N * 128 * sizeof(__half));   // layer-1 gemm out
    __half* Ah2   = (__half*)alloc((size_t)N * 128 * sizeof(__half));   // layer-2 gemm out
    int*   count  = (int*)alloc((size_t)N * sizeof(int));
    unsigned short* rank = (unsigned short*)alloc((size_t)E * sizeof(unsigned short));
    int2*  ell    = (int2*)alloc((size_t)N * ELLK * sizeof(int2));
    float* pooled = (float*)alloc(64 * 128 * sizeof(float));
    float* cnt    = (float*)alloc(64 * sizeof(float));
    unsigned short* W1h = (unsigned short*)alloc(16384 * sizeof(short));
    unsigned short* W1l = (unsigned short*)alloc(16384 * sizeof(short));
    unsigned short* W2h = (unsigned short*)alloc(16384 * sizeof(short));
    unsigned short* W2l = (unsigned short*)alloc(16384 * sizeof(short));

    int hb2 = (E + 511) / 512;              // 512-wide edge blocks (1172)
    int nzb = (N + 255) / 256;              // node-parallel pad blocks (196)
    int g2blocks = (N + 31) / 32;           // gemm-1 blocks (1563)
    int ggblocks = (N + GG - 1) / GG;       // gather_gemm blocks (1563)
    int pblocks = (N + PB - 1) / PB;        // gather_pool blocks (1563)
    int zb = (N + 8256 + 255) / 256;        // zero blocks (count+pooled+cnt)

    // #1: weight conv + zero everything
    wconv_zero<<<128 + zb, 256, 0, stream>>>(W1, W2, W1h, W1l, W2h, W2l,
                                             count, pooled, cnt, N);

    // #2: GEMM-1 (high-occupancy 32-row tiles) overlapped with hist+rank
    fused_hg<<<g2blocks + hb2, 512, 0, stream>>>(x, W1h, W1l, Ah, N, g2blocks,
                                                 dst, count, rank, E);

    // #3: packed (src,norm) ELL fill (2 edges/thread) + zero-pad to 16-groups
    scatter_norm<<<hb2 + nzb, 256, 0, stream>>>(src, dst, rank, count, ell, E, N, hb2);

    // #4: layer-1 aggregation fused with layer-2 GEMM
    gather_gemm<<<ggblocks, 512, 0, stream>>>(Ah, b1, count, (const long long*)ell,
                                              W2h, W2l, Ah2, N);

    // #5: layer-2 aggregation fused with pool (LDS P + block run-length)
    gather_pool<<<pblocks, 512, 0, stream>>>(Ah2, b2, count, (const long long*)ell,
                                             batch, pooled, cnt, N);

    // #6: head
    head_kernel<<<64, 64, 0, stream>>>(pooled, cnt, Wfc1, bfc1, Wfc2, bfc2, out);
}

// Round 15
// 209.668 us; speedup vs baseline: 1.0283x; 1.0283x over previous
//
#include <hip/hip_runtime.h>
#include <hip/hip_fp16.h>

// ---------------------------------------------------------------------------
// GCN pipeline. Round 28 = exact r13 revert (validated best, 211.1 us).
//  - r14's GEMM-1 32-row tile (2x W L2 traffic on overlapped leg) and
//    scatter 2-edge unroll both regressed -> reverted.
//  - Config: ELL+rank (scan-free CSR), fused GEMM-1/hist, em-in-LDS gathers
//    at 32 waves/CU (GG=PB=32), LDS-P block pool, 6 dispatches.
// ---------------------------------------------------------------------------

#define ELLK 48   // mult of 16
#define PB   32   // nodes per gather_pool block
#define GG   32   // nodes per gather_gemm block

typedef short bf16x8 __attribute__((ext_vector_type(8)));
typedef float f32x4  __attribute__((ext_vector_type(4)));

__device__ inline unsigned short f2bf_rne(float f) {
    unsigned u = __float_as_uint(f);
    unsigned r = (u + 0x7fffu + ((u >> 16) & 1u)) >> 16;
    return (unsigned short)r;
}
__device__ inline float bf2f(unsigned short h) {
    return __uint_as_float(((unsigned)h) << 16);
}

// ---- dispatch #1: weight split/transpose + zero(count, pooled, cnt) -----
__global__ __launch_bounds__(256) void wconv_zero(const float* __restrict__ W1,
                                                  const float* __restrict__ W2,
                                                  unsigned short* __restrict__ W1h,
                                                  unsigned short* __restrict__ W1l,
                                                  unsigned short* __restrict__ W2h,
                                                  unsigned short* __restrict__ W2l,
                                                  int* __restrict__ count,
                                                  float* __restrict__ pooled,
                                                  float* __restrict__ cnt, int N) {
    int tid = threadIdx.x;
    int b = blockIdx.x;
    if (b < 128) {
        int i = b * 256 + tid;               // 0..32767
        const float* W = (i < 16384) ? W1 : W2;
        unsigned short* Wh = (i < 16384) ? W1h : W2h;
        unsigned short* Wl = (i < 16384) ? W1l : W2l;
        int ii = i & 16383;
        int k = ii >> 7, n = ii & 127;
        float v = W[ii];
        unsigned short h = f2bf_rne(v);
        float lo = v - bf2f(h);
        int ct = n >> 4, nn = n & 15, ks = k >> 5, q = (k >> 3) & 3, j = k & 7;
        int oidx = (((ct * 4 + ks) * 64) + (q * 16 + nn)) * 8 + j;
        Wh[oidx] = h;
        Wl[oidx] = f2bf_rne(lo);
    } else {
        int idx = (b - 128) * 256 + tid;
        if (idx < N) count[idx] = 0;
        else if (idx < N + 8192) pooled[idx - N] = 0.f;
        else if (idx < N + 8256) cnt[idx - N - 8192] = 0.f;
    }
}

// ---- GEMM body (256t, 4-wave): OUT_fp16 = act(X_f32) @ W, bf16x3 MFMA ---
template <bool RELU_IN>
__device__ __forceinline__ void gemm_body(const float* __restrict__ X,
                                          const unsigned short* __restrict__ Wfh,
                                          const unsigned short* __restrict__ Wfl,
                                          __half* __restrict__ OUT, int M, int blk) {
    __shared__ unsigned short Xh[64][136];
    __shared__ unsigned short Xl[64][136];
    int tid = threadIdx.x;
    int w = tid >> 6, l = tid & 63;
    int m0 = blk * 64;

#pragma unroll
    for (int it = 0; it < 8; it++) {
        int i = tid + it * 256;
        int row = i >> 5, c4 = i & 31;
        int grow = m0 + row;
        float4 v = make_float4(0.f, 0.f, 0.f, 0.f);
        if (grow < M) v = *(const float4*)(X + (size_t)grow * 128 + c4 * 4);
        if (RELU_IN) {
            v.x = fmaxf(v.x, 0.f); v.y = fmaxf(v.y, 0.f);
            v.z = fmaxf(v.z, 0.f); v.w = fmaxf(v.w, 0.f);
        }
        float a[4] = {v.x, v.y, v.z, v.w};
        ushort4 hi, lo;
        unsigned short* hp = (unsigned short*)&hi;
        unsigned short* lp = (unsigned short*)&lo;
#pragma unroll
        for (int e = 0; e < 4; e++) {
            unsigned short h = f2bf_rne(a[e]);
            hp[e] = h;
            lp[e] = f2bf_rne(a[e] - bf2f(h));
        }
        *(ushort4*)&Xh[row][c4 * 4] = hi;
        *(ushort4*)&Xl[row][c4 * 4] = lo;
    }
    __syncthreads();

    int q = l >> 4, nn = l & 15;
    f32x4 acc[8];
#pragma unroll
    for (int ct = 0; ct < 8; ct++) acc[ct] = (f32x4){0.f, 0.f, 0.f, 0.f};

#pragma unroll
    for (int ks = 0; ks < 4; ks++) {
        bf16x8 ahi = *(const bf16x8*)&Xh[w * 16 + nn][ks * 32 + q * 8];
        bf16x8 alo = *(const bf16x8*)&Xl[w * 16 + nn][ks * 32 + q * 8];
#pragma unroll
        for (int ct = 0; ct < 8; ct++) {
            size_t fo = ((size_t)(ct * 4 + ks) * 64 + l) * 8;
            bf16x8 bhi = *(const bf16x8*)(Wfh + fo);
            bf16x8 blo = *(const bf16x8*)(Wfl + fo);
            acc[ct] = __builtin_amdgcn_mfma_f32_16x16x32_bf16(ahi, bhi, acc[ct], 0, 0, 0);
            acc[ct] = __builtin_amdgcn_mfma_f32_16x16x32_bf16(alo, bhi, acc[ct], 0, 0, 0);
            acc[ct] = __builtin_amdgcn_mfma_f32_16x16x32_bf16(ahi, blo, acc[ct], 0, 0, 0);
        }
    }
    __syncthreads();   // done with Xh — reuse as fp16 epilogue buffer

#pragma unroll
    for (int r = 0; r < 4; r++) {
        int lrow = w * 16 + q * 4 + r;
#pragma unroll
        for (int ct = 0; ct < 8; ct++) {
            __half hv = __float2half(acc[ct][r]);
            Xh[lrow][ct * 16 + nn] = __half_as_ushort(hv);
        }
    }
    __syncthreads();
#pragma unroll
    for (int t = 0; t < 4; t++) {
        int c = tid + t * 256;
        int row = c >> 4, seg = c & 15;
        int grow = m0 + row;
        if (grow < M) {
            uint4 v = *(uint4*)&Xh[row][seg * 8];
            *(uint4*)((unsigned short*)OUT + (size_t)grow * 128 + seg * 8) = v;
        }
    }
}

// fat kernel: blocks [0,gblocks) = GEMM-1; blocks >= gblocks = hist+rank.
__global__ __launch_bounds__(256) void fused_hg(const float* __restrict__ X,
                                                const unsigned short* __restrict__ Wfh,
                                                const unsigned short* __restrict__ Wfl,
                                                __half* __restrict__ OUT, int M, int gblocks,
                                                const int* __restrict__ dst,
                                                int* __restrict__ count,
                                                unsigned short* __restrict__ rank, int E) {
    if ((int)blockIdx.x < gblocks) {
        gemm_body<false>(X, Wfh, Wfl, OUT, M, blockIdx.x);
    } else {
        int e = ((int)blockIdx.x - gblocks) * 256 + (int)threadIdx.x;
        if (e < E) {
            int d = dst[e];
            rank[e] = (unsigned short)atomicAdd(&count[d], 1);
        }
    }
}

// scatter leg (blocks < hb): atomic-free packed ELL fill.
// pad leg: zero (src=0,norm=0) slots [count, ceil16] (min 16) per node.
__global__ void scatter_norm(const int* __restrict__ src, const int* __restrict__ dst,
                             const unsigned short* __restrict__ rank,
                             const int* __restrict__ count,
                             int2* __restrict__ ell, int E, int N, int hb) {
    int b = blockIdx.x;
    if (b < hb) {
        int e = b * 256 + (int)threadIdx.x;
        if (e < E) {
            int s = src[e], d = dst[e];
            int r = rank[e];
            float ds = 1.0f / sqrtf((float)count[s] + 1.0f);
            float dd = 1.0f / sqrtf((float)count[d] + 1.0f);
            if (r < ELLK) ell[(size_t)d * ELLK + r] = make_int2(s, __float_as_int(ds * dd));
        }
    } else {
        int n = (b - hb) * 256 + (int)threadIdx.x;
        if (n < N) {
            int r = min(count[n], ELLK);
            int rend = min(ELLK, max(16, (r + 15) & ~15));
            int2 z = make_int2(0, 0);
            for (int j = r; j < rend; j++) ell[(size_t)n * ELLK + j] = z;
        }
    }
}

// ---- 8B-row fma: 4 halves * weight into a[4] ----------------------------
__device__ __forceinline__ void fma4(uint2 raw, float nr, float a[4]) {
    __half2 h0 = *(__half2*)&raw.x, h1 = *(__half2*)&raw.y;
    float2 f0 = __half22float2(h0), f1 = __half22float2(h1);
    a[0] = fmaf(f0.x, nr, a[0]); a[1] = fmaf(f0.y, nr, a[1]);
    a[2] = fmaf(f1.x, nr, a[2]); a[3] = fmaf(f1.y, nr, a[3]);
}

// ---- one node, em from LDS (32 slots staged), 8 loads in flight ---------
__device__ __forceinline__ void gather_node8(const unsigned short* __restrict__ hb,
                                             const long long* __restrict__ em_row,   // LDS
                                             const long long* __restrict__ ell_row,  // global (tail)
                                             int n, int cn, int sub2, int cl2,
                                             float a[4]) {
    int2 v[8];
#pragma unroll
    for (int k = 0; k < 8; k++) *(long long*)&v[k] = em_row[sub2 + k * 2];
    float din = 1.0f / sqrtf((float)cn + 1.0f);
    uint2 sr = *(const uint2*)(hb + (size_t)n * 128 + cl2 * 4);
    uint2 r[8];
#pragma unroll
    for (int k = 0; k < 8; k++) r[k] = *(const uint2*)(hb + (size_t)v[k].x * 128 + cl2 * 4);
    fma4(sr, sub2 == 0 ? din * din : 0.f, a);
#pragma unroll
    for (int k = 0; k < 8; k++) fma4(r[k], __int_as_float(v[k].y), a);
    if (cn > 16) {                       // wave-uniform branch (~10% of nodes)
        int2 u[8];
#pragma unroll
        for (int k = 0; k < 8; k++) *(long long*)&u[k] = em_row[16 + sub2 + k * 2];
        uint2 q[8];
#pragma unroll
        for (int k = 0; k < 8; k++) q[k] = *(const uint2*)(hb + (size_t)u[k].x * 128 + cl2 * 4);
#pragma unroll
        for (int k = 0; k < 8; k++) fma4(q[k], __int_as_float(u[k].y), a);
        if (cn > 32) {                   // ~never; global ELL slots 32..47
#pragma unroll
            for (int k = 0; k < 8; k++) {
                long long vv = ell_row[32 + sub2 + k * 2];
                uint2 qq = *(const uint2*)(hb + (size_t)(int)vv * 128 + cl2 * 4);
                fma4(qq, __int_as_float((int)(vv >> 32)), a);
            }
        }
    }
}

// ---- FUSED gather1 + gemm2 (512t, GG=32 nodes/block): Ah,ell -> Ah2 -----
// LDS ~= 25KB -> 4 blocks/CU (wave-limited, 32 waves/CU).
__global__ __launch_bounds__(512) void gather_gemm(const __half* __restrict__ h,
                                                   const float* __restrict__ bias,
                                                   const int* __restrict__ count,
                                                   const long long* __restrict__ ell,
                                                   const unsigned short* __restrict__ Wfh,
                                                   const unsigned short* __restrict__ Wfl,
                                                   __half* __restrict__ OUT, int N) {
    __shared__ long long em_l[GG * 32];          // 8 KB
    __shared__ int cnt_l[GG];
    __shared__ unsigned short Xh[GG][136];       // 8.7 KB
    __shared__ unsigned short Xl[GG][136];
    int tid = threadIdx.x;
    int w = tid >> 6, l = tid & 63;
    int sub2 = l >> 5, cl2 = l & 31;
    int m0 = blockIdx.x * GG;
    const unsigned short* hb = (const unsigned short*)h;

    // stage em (32 slots/node) + counts, coalesced
    for (int i = tid; i < GG * 32; i += 512) {
        int node = i >> 5, slot = i & 31;
        int ne = min(m0 + node, N - 1);
        em_l[i] = ell[(size_t)ne * ELLK + slot];
    }
    if (tid < GG) cnt_l[tid] = count[min(m0 + tid, N - 1)];
    __syncthreads();

    float b4[4];
#pragma unroll
    for (int k = 0; k < 4; k++) b4[k] = bias[cl2 * 4 + k];

    // Phase A: 4 nodes per wave
    for (int rr = 0; rr < 4; rr++) {
        int lrow = w * 4 + rr;
        int n = m0 + lrow;
        int ne = min(n, N - 1);
        float a[4] = {0.f, 0.f, 0.f, 0.f};
        gather_node8(hb, em_l + lrow * 32, ell + (size_t)ne * ELLK,
                     ne, cnt_l[lrow], sub2, cl2, a);
#pragma unroll
        for (int k = 0; k < 4; k++) a[k] += __shfl_xor(a[k], 32, 64);
        if (sub2 == 0) {
            unsigned short hs[4], ls[4];
#pragma unroll
            for (int k = 0; k < 4; k++) {
                float vv = fmaxf(a[k] + b4[k], 0.f);
                unsigned short hh = f2bf_rne(vv);
                hs[k] = hh;
                ls[k] = f2bf_rne(vv - bf2f(hh));
            }
            *(ushort4*)&Xh[lrow][cl2 * 4] = *(ushort4*)hs;
            *(ushort4*)&Xl[lrow][cl2 * 4] = *(ushort4*)ls;
        }
    }
    __syncthreads();

    // Phase B: 8-wave MFMA over 32x128 tile
    // wave w: row-half w2 = w&1 (rows w2*16..+15), col-pair ch = (w>>1)*2
    int q = l >> 4, nn = l & 15;
    int w2 = w & 1;
    int ch = (w >> 1) * 2;
    f32x4 acc[2];
#pragma unroll
    for (int ct2 = 0; ct2 < 2; ct2++) acc[ct2] = (f32x4){0.f, 0.f, 0.f, 0.f};
#pragma unroll
    for (int ks = 0; ks < 4; ks++) {
        bf16x8 ahi = *(const bf16x8*)&Xh[w2 * 16 + nn][ks * 32 + q * 8];
        bf16x8 alo = *(const bf16x8*)&Xl[w2 * 16 + nn][ks * 32 + q * 8];
#pragma unroll
        for (int ct2 = 0; ct2 < 2; ct2++) {
            int ct = ch + ct2;
            size_t fo = ((size_t)(ct * 4 + ks) * 64 + l) * 8;
            bf16x8 bhi = *(const bf16x8*)(Wfh + fo);
            bf16x8 blo = *(const bf16x8*)(Wfl + fo);
            acc[ct2] = __builtin_amdgcn_mfma_f32_16x16x32_bf16(ahi, bhi, acc[ct2], 0, 0, 0);
            acc[ct2] = __builtin_amdgcn_mfma_f32_16x16x32_bf16(alo, bhi, acc[ct2], 0, 0, 0);
            acc[ct2] = __builtin_amdgcn_mfma_f32_16x16x32_bf16(ahi, blo, acc[ct2], 0, 0, 0);
        }
    }
    __syncthreads();   // reuse Xh as fp16 epilogue buffer
#pragma unroll
    for (int r = 0; r < 4; r++) {
        int lrow = w2 * 16 + q * 4 + r;
#pragma unroll
        for (int ct2 = 0; ct2 < 2; ct2++) {
            __half hv = __float2half(acc[ct2][r]);
            Xh[lrow][(ch + ct2) * 16 + nn] = __half_as_ushort(hv);
        }
    }
    __syncthreads();
    {
        int c = tid;                            // 512 = 32 rows x 16 segs
        int row = c >> 4, seg = c & 15;
        int grow = m0 + row;
        if (grow < N) {
            uint4 v = *(uint4*)&Xh[row][seg * 8];
            *(uint4*)((unsigned short*)OUT + (size_t)grow * 128 + seg * 8) = v;
        }
    }
}

// ---- FUSED gather2 + pool (512t, 32 nodes/block): -> pooled/cnt ---------
// LDS = 8KB em + 16KB P + small ~= 24.8KB -> 4 blocks/CU (wave-limited).
__global__ __launch_bounds__(512) void gather_pool(const __half* __restrict__ h,
                                                   const float* __restrict__ bias,
                                                   const int* __restrict__ count,
                                                   const long long* __restrict__ ell,
                                                   const int* __restrict__ batch,
                                                   float* __restrict__ pooled,
                                                   float* __restrict__ cnt, int N) {
    __shared__ long long em_l[PB * 32];          // 8 KB
    __shared__ int cnt_l[PB];
    __shared__ float P[PB][128];                 // 16 KB
    __shared__ int gb[PB];
    int tid = threadIdx.x;
    int w = tid >> 6, l = tid & 63;
    int sub2 = l >> 5, cl2 = l & 31;
    int m0 = blockIdx.x * PB;
    const unsigned short* hb = (const unsigned short*)h;

    for (int i = tid; i < PB * 32; i += 512) {
        int node = i >> 5, slot = i & 31;
        int ne = min(m0 + node, N - 1);
        em_l[i] = ell[(size_t)ne * ELLK + slot];
    }
    if (tid < PB) {
        cnt_l[tid] = count[min(m0 + tid, N - 1)];
        gb[tid] = (m0 + tid < N) ? batch[m0 + tid] : -1;
    }
    __syncthreads();

    float b4[4];
#pragma unroll
    for (int k = 0; k < 4; k++) b4[k] = bias[cl2 * 4 + k];

    // Phase A: 4 nodes per wave, results into P
    for (int rr = 0; rr < 4; rr++) {
        int lrow = w * 4 + rr;
        int n = m0 + lrow;
        int ne = min(n, N - 1);
        float a[4] = {0.f, 0.f, 0.f, 0.f};
        gather_node8(hb, em_l + lrow * 32, ell + (size_t)ne * ELLK,
                     ne, cnt_l[lrow], sub2, cl2, a);
#pragma unroll
        for (int k = 0; k < 4; k++) a[k] += __shfl_xor(a[k], 32, 64);
        if (sub2 == 0) {
            float4 o;
            o.x = fmaxf(a[0] + b4[0], 0.f);
            o.y = fmaxf(a[1] + b4[1], 0.f);
            o.z = fmaxf(a[2] + b4[2], 0.f);
            o.w = fmaxf(a[3] + b4[3], 0.f);
            *(float4*)&P[lrow][cl2 * 4] = o;
        }
    }
    __syncthreads();

    // Phase B: run-length pool, 2 half-groups x 16 rows (threads < 256)
    if (tid < 256) {
        int c = tid & 127, half = tid >> 7;
        float acc = 0.f, cacc = 0.f;
        int curg = -1;
        for (int i = half * 16; i < half * 16 + 16; i++) {
            int n = m0 + i;
            if (n >= N) break;
            int g = gb[i];
            float v = P[i][c];
            if (g != curg) {
                if (curg >= 0) {
                    atomicAdd(&pooled[curg * 128 + c], acc);
                    if (c == 0) atomicAdd(&cnt[curg], cacc);
                }
                curg = g; acc = 0.f; cacc = 0.f;
            }
            acc += v; cacc += 1.f;
        }
        if (curg >= 0) {
            atomicAdd(&pooled[curg * 128 + c], acc);
            if (c == 0) atomicAdd(&cnt[curg], cacc);
        }
    }
}

// ---- head: one wave per graph ------------------------------------------
__global__ __launch_bounds__(64) void head_kernel(const float* __restrict__ pooled,
                                                  const float* __restrict__ cnt,
                                                  const float* __restrict__ Wfc1,
                                                  const float* __restrict__ bfc1,
                                                  const float* __restrict__ Wfc2,
                                                  const float* __restrict__ bfc2,
                                                  float* __restrict__ out) {
    __shared__ float mean[128];
    int g = blockIdx.x;
    int t = threadIdx.x;
    float inv = 1.0f / fmaxf(cnt[g], 1.0f);
    mean[t] = pooled[g * 128 + t] * inv;
    mean[t + 64] = pooled[g * 128 + t + 64] * inv;
    __syncthreads();
    float s = bfc1[t];
#pragma unroll 4
    for (int k = 0; k < 128; k++) s = fmaf(mean[k], Wfc1[k * 64 + t], s);
    float p = fmaxf(s, 0.f) * Wfc2[t];
#pragma unroll
    for (int o = 32; o > 0; o >>= 1) p += __shfl_down(p, o, 64);
    if (t == 0) out[g] = p + bfc2[0];
}

extern "C" void kernel_launch(void* const* d_in, const int* in_sizes, int n_in,
                              void* d_out, int out_size, void* d_ws, size_t ws_size,
                              hipStream_t stream) {
    const float* x    = (const float*)d_in[0];
    const int*   edge = (const int*)d_in[1];
    const int*   batch= (const int*)d_in[2];
    const float* W1   = (const float*)d_in[3];
    const float* b1   = (const float*)d_in[4];
    const float* W2   = (const float*)d_in[5];
    const float* b2   = (const float*)d_in[6];
    const float* Wfc1 = (const float*)d_in[7];
    const float* bfc1 = (const float*)d_in[8];
    const float* Wfc2 = (const float*)d_in[9];
    const float* bfc2 = (const float*)d_in[10];
    float* out = (float*)d_out;

    int N = in_sizes[0] / 128;
    int E = in_sizes[1] / 2;
    const int* src = edge;
    const int* dst = edge + E;

    char* ws = (char*)d_ws;
    size_t off = 0;
    auto alloc = [&](size_t bytes) { void* p = ws + off; off += (bytes + 255) & ~(size_t)255; return p; };
    __half* Ah    = (__half*)alloc((size_t)N * 128 * sizeof(__half));   // layer-1 gemm out
    __half* Ah2   = (__half*)alloc((size_t)N * 128 * sizeof(__half));   // layer-2 gemm out
    int*   count  = (int*)alloc((size_t)N * sizeof(int));
    unsigned short* rank = (unsigned short*)alloc((size_t)E * sizeof(unsigned short));
    int2*  ell    = (int2*)alloc((size_t)N * ELLK * sizeof(int2));
    float* pooled = (float*)alloc(64 * 128 * sizeof(float));
    float* cnt    = (float*)alloc(64 * sizeof(float));
    unsigned short* W1h = (unsigned short*)alloc(16384 * sizeof(short));
    unsigned short* W1l = (unsigned short*)alloc(16384 * sizeof(short));
    unsigned short* W2h = (unsigned short*)alloc(16384 * sizeof(short));
    unsigned short* W2l = (unsigned short*)alloc(16384 * sizeof(short));

    int hb = (E + 255) / 256;               // edge-parallel blocks (2344)
    int nzb = (N + 255) / 256;              // node-parallel pad blocks (196)
    int gblocks = (N + 63) / 64;            // gemm-1 blocks (782)
    int ggblocks = (N + GG - 1) / GG;       // gather_gemm blocks (1563)
    int pblocks = (N + PB - 1) / PB;        // gather_pool blocks (1563)
    int zb = (N + 8256 + 255) / 256;        // zero blocks (count+pooled+cnt)

    // #1: weight conv + zero everything
    wconv_zero<<<128 + zb, 256, 0, stream>>>(W1, W2, W1h, W1l, W2h, W2l,
                                             count, pooled, cnt, N);

    // #2: GEMM-1 overlapped with hist+rank (independent work)
    fused_hg<<<gblocks + hb, 256, 0, stream>>>(x, W1h, W1l, Ah, N, gblocks,
                                               dst, count, rank, E);

    // #3: packed (src,norm) ELL fill + zero-pad to 16-groups
    scatter_norm<<<hb + nzb, 256, 0, stream>>>(src, dst, rank, count, ell, E, N, hb);

    // #4: layer-1 aggregation fused with layer-2 GEMM
    gather_gemm<<<ggblocks, 512, 0, stream>>>(Ah, b1, count, (const long long*)ell,
                                              W2h, W2l, Ah2, N);

    // #5: layer-2 aggregation fused with pool (LDS P + block run-length)
    gather_pool<<<pblocks, 512, 0, stream>>>(Ah2, b2, count, (const long long*)ell,
                                             batch, pooled, cnt, N);

    // #6: head
    head_kernel<<<64, 64, 0, stream>>>(pooled, cnt, Wfc1, bfc1, Wfc2, bfc2, out);
}